// Round 6
// baseline (62.078 us; speedup 1.0000x reference)
//
#include <hip/hip_runtime.h>
#include <math.h>

#define IH 512
#define IW 512
#define NPX (IH*IW)
#define TS 32
#define YHALO 7              // 5 (search) + 2 (patch)
#define RHALO 5
#define YD (TS + 2*YHALO)    // 46
#define RD (TS + 2*RHALO)    // 42
#define RSZ (RD*RD)
#define YSZ (YD*YD)          // 2116

#define FSQRT(x) __builtin_amdgcn_sqrtf(x)
#if __has_builtin(__builtin_amdgcn_exp2f)
#define FEXP2(x) __builtin_amdgcn_exp2f(x)
#else
#define FEXP2(x) exp2f(x)
#endif

// ---------------- split compute kernel: dx-group per blockIdx.z --------------
// Round-5 post-mortem: compiler refused to keep the 8x5 rolling window in
// registers (VGPR=76) -> ~52 LDS reads/shift; LDS-pipe bound. This version:
// (a) parity-duplicated Y (Ye + Yo shifted 1 col) so each 5-float window row
//     is 3x ds_read_b64 (24 reads/shift instead of 40),
// (b) RGB read direct from global (L2-resident 3MB image, coalesced) -- no RGB
//     staging, no 21KB RGB LDS,
// (c) cross-term hs = ybsq + winsq - 2*dot with rolling winsq (box clamped >=0
//     against FP-cancellation NaN),
// (d) exp2 with -log2(e)/h folded.
// NO min-waves clamp (round-2: (256,4) forced VGPR=64 -> 0.5GB spill).
__global__ __launch_bounds__(256)
void nlm_part(const float* __restrict__ rgb,
              const float* __restrict__ sigma,
              float4* __restrict__ ws) {
    __shared__ float Ye[YSZ];
    __shared__ float Yo[YSZ];

    const int tid = threadIdx.x;
    const int tx0 = blockIdx.x * TS;
    const int ty0 = blockIdx.y * TS;
    const int slice = blockIdx.z;
    const int nz = gridDim.z;

    const float* Rp = rgb;
    const float* Gp = rgb + NPX;
    const float* Bp = rgb + 2 * NPX;

    for (int idx = tid; idx < YSZ; idx += 256) {
        int a = idx / YD, b = idx - a * YD;
        int gy = (ty0 + a - YHALO) & (IH - 1);
        int gx = (tx0 + b - YHALO) & (IW - 1);
        int g = gy * IW + gx;
        float y = 0.299f * Rp[g] + 0.587f * Gp[g] + 0.114f * Bp[g];
        Ye[idx] = y;
        if (b > 0) Yo[idx - 1] = y;   // Yo[a][m] = Y[a][m+1]
    }
    __syncthreads();

    // w = exp(-d/h) = 2^(d * m2),  m2 = -log2(e)/h
    const float m2 = -1.4426950408889634f /
                     (fmaxf(sigma[0] * 2.0f, 0.0f) + 1e-6f);

    const int tx = tid & 31;
    const int tz = tid >> 5;
    const int r0 = tz * 4;

    // base-Y patch in registers + per-row sum of squares
    const int ybase = (YHALO + r0 - 2) * YD + (YHALO + tx - 2);
    float yb[8][5];
    float ybsq[8];
    #pragma unroll
    for (int i = 0; i < 8; ++i) {
        float s = 0.f;
        #pragma unroll
        for (int b = 0; b < 5; ++b) {
            float v = Ye[ybase + i * YD + b];
            yb[i][b] = v;
            s = fmaf(v, v, s);
        }
        ybsq[i] = s;
    }

    // rgb row bases (element index, row<<9), rows r0-5 .. r0+8; static-indexed
    int rb[14];
    #pragma unroll
    for (int q = 0; q < 14; ++q)
        rb[q] = ((ty0 + r0 - 5 + q) & (IH - 1)) << 9;

    float accR[4] = {0.f, 0.f, 0.f, 0.f};
    float accG[4] = {0.f, 0.f, 0.f, 0.f};
    float accB[4] = {0.f, 0.f, 0.f, 0.f};
    float den[4]  = {0.f, 0.f, 0.f, 0.f};

    int dxlo, dxcnt;
    if (nz == 6) { if (slice < 5) { dxlo = -5 + 2 * slice; dxcnt = 2; }
                   else           { dxlo = 5;              dxcnt = 1; } }
    else         { if (slice < 3) { dxlo = -5 + 3 * slice; dxcnt = 3; }
                   else           { dxlo = 4;              dxcnt = 2; } }

    for (int u = 0; u < dxcnt; ++u) {
        const int dx  = dxlo + u;
        const int col = (tx0 + tx - dx) & (IW - 1);     // rgb column
        const int c   = YHALO + tx - 2 - dx;            // window col start 0..41
        const float* Yb_ = (c & 1) ? Yo : Ye;
        const int ci  = (c & 1) ? (c - 1) : c;          // even
        // window rows r0-7..r0+10 -> LDS rows r0..r0+17 (YHALO=7)
        const float2* wbase =
            reinterpret_cast<const float2*>(Yb_ + r0 * YD + ci);

        float winsq[8];
        #pragma unroll
        for (int k = 0; k <= 10; ++k) {                 // dy = 5 - k
            float hs[8];
            #pragma unroll
            for (int i = 0; i < 8; ++i) {
                const int j = i + k;                    // window row 0..17
                float2 w0 = wbase[j * (YD / 2) + 0];
                float2 w1 = wbase[j * (YD / 2) + 1];
                float2 w2 = wbase[j * (YD / 2) + 2];
                // win = {w0.x, w0.y, w1.x, w1.y, w2.x}
                float cr = yb[i][0] * w0.x;
                cr = fmaf(yb[i][1], w0.y, cr);
                cr = fmaf(yb[i][2], w1.x, cr);
                cr = fmaf(yb[i][3], w1.y, cr);
                cr = fmaf(yb[i][4], w2.x, cr);
                if (k == 0 || i == 7) {                 // first appearance of row j
                    float s = w0.x * w0.x;
                    s = fmaf(w0.y, w0.y, s);
                    s = fmaf(w1.x, w1.x, s);
                    s = fmaf(w1.y, w1.y, s);
                    s = fmaf(w2.x, w2.x, s);
                    winsq[j & 7] = s;
                }
                hs[i] = fmaf(-2.f, cr, ybsq[i] + winsq[j & 7]);
            }
            float pre[9];
            pre[0] = 0.f;
            #pragma unroll
            for (int i = 0; i < 8; ++i) pre[i + 1] = pre[i] + hs[i];
            #pragma unroll
            for (int rr = 0; rr < 4; ++rr) {
                float box = fmaxf(pre[rr + 5] - pre[rr], 0.f);  // FP cancel guard
                float w = FEXP2(FSQRT(box) * m2);
                const int off = rb[rr + k] + col;       // static rb index
                accR[rr] = fmaf(w, Rp[off], accR[rr]);
                accG[rr] = fmaf(w, Gp[off], accG[rr]);
                accB[rr] = fmaf(w, Bp[off], accB[rr]);
                den[rr] += w;
            }
        }
    }

    #pragma unroll
    for (int rr = 0; rr < 4; ++rr) {
        int px = (ty0 + r0 + rr) * IW + tx0 + tx;
        ws[(size_t)slice * NPX + px] =
            make_float4(accR[rr], accG[rr], accB[rr], den[rr]);
    }
}

// ---------------- combine: sum nslice slices, normalize, clip ----------------
__global__ __launch_bounds__(256)
void nlm_combine(const float4* __restrict__ ws, float* __restrict__ out,
                 int nslice) {
    int px = blockIdx.x * 256 + threadIdx.x;
    float r = 0.f, g = 0.f, b = 0.f, w = 0.f;
    for (int s = 0; s < nslice; ++s) {
        float4 v = ws[(size_t)s * NPX + px];
        r += v.x; g += v.y; b += v.z; w += v.w;
    }
    float iw = 1.0f / w;
    out[px]           = fminf(fmaxf(r * iw, 0.f), 1.f);
    out[NPX + px]     = fminf(fmaxf(g * iw, 0.f), 1.f);
    out[2 * NPX + px] = fminf(fmaxf(b * iw, 0.f), 1.f);
}

// ---------------- fallback: monolithic kernel (ws too small) -----------------
__global__ __launch_bounds__(256)
void nlm_mono(const float* __restrict__ rgb,
              const float* __restrict__ sigma,
              float* __restrict__ out) {
    __shared__ float Y[YSZ];
    __shared__ float RGBL[3 * RSZ];

    const int tid = threadIdx.x;
    const int tx0 = blockIdx.x * TS;
    const int ty0 = blockIdx.y * TS;

    const float* Rp = rgb;
    const float* Gp = rgb + NPX;
    const float* Bp = rgb + 2 * NPX;

    for (int idx = tid; idx < YSZ; idx += 256) {
        int a = idx / YD, b = idx - a * YD;
        int gy = (ty0 + a - YHALO) & (IH - 1);
        int gx = (tx0 + b - YHALO) & (IW - 1);
        int g = gy * IW + gx;
        Y[idx] = 0.299f * Rp[g] + 0.587f * Gp[g] + 0.114f * Bp[g];
    }
    for (int idx = tid; idx < RSZ; idx += 256) {
        int a = idx / RD, b = idx - a * RD;
        int gy = (ty0 + a - RHALO) & (IH - 1);
        int gx = (tx0 + b - RHALO) & (IW - 1);
        int g = gy * IW + gx;
        RGBL[idx]           = Rp[g];
        RGBL[RSZ + idx]     = Gp[g];
        RGBL[2 * RSZ + idx] = Bp[g];
    }
    __syncthreads();

    const float minv_h = -1.0f / (fmaxf(sigma[0] * 2.0f, 0.0f) + 1e-6f);
    const int tx = tid & 31;
    const int tz = tid >> 5;
    const int r0 = tz * 4;

    const int ybase = (YHALO + r0 - 2) * YD + (YHALO + tx - 2);
    float yb[8][5];
    #pragma unroll
    for (int i = 0; i < 8; ++i)
        #pragma unroll
        for (int b = 0; b < 5; ++b)
            yb[i][b] = Y[ybase + i * YD + b];

    float accR[4] = {0.f,0.f,0.f,0.f}, accG[4] = {0.f,0.f,0.f,0.f};
    float accB[4] = {0.f,0.f,0.f,0.f}, den[4] = {0.f,0.f,0.f,0.f};

    for (int dx = -5; dx <= 5; ++dx) {
        const int ybd = (YHALO + r0 - 7) * YD + (YHALO + tx - 2 - dx);
        const int rbd = (RHALO + r0 - 5) * RD + (RHALO + tx - dx);

        #pragma unroll
        for (int k = 0; k <= 10; ++k) {
            float hs[8];
            #pragma unroll
            for (int i = 0; i < 8; ++i) {
                float s = 0.f;
                #pragma unroll
                for (int b = 0; b < 5; ++b) {
                    float d = yb[i][b] - Y[ybd + (i + k) * YD + b];
                    s = fmaf(d, d, s);
                }
                hs[i] = s;
            }
            float pre[9];
            pre[0] = 0.f;
            #pragma unroll
            for (int i = 0; i < 8; ++i) pre[i + 1] = pre[i] + hs[i];
            #pragma unroll
            for (int rr = 0; rr < 4; ++rr) {
                float box = pre[rr + 5] - pre[rr];
                float w = __expf(FSQRT(box) * minv_h);
                const int s2 = rbd + (rr + k) * RD;
                accR[rr] = fmaf(w, RGBL[s2], accR[rr]);
                accG[rr] = fmaf(w, RGBL[RSZ + s2], accG[rr]);
                accB[rr] = fmaf(w, RGBL[2 * RSZ + s2], accB[rr]);
                den[rr] += w;
            }
        }
    }

    #pragma unroll
    for (int rr = 0; rr < 4; ++rr) {
        int px = (ty0 + r0 + rr) * IW + tx0 + tx;
        float iw = 1.0f / den[rr];
        out[px]           = fminf(fmaxf(accR[rr] * iw, 0.f), 1.f);
        out[NPX + px]     = fminf(fmaxf(accG[rr] * iw, 0.f), 1.f);
        out[2 * NPX + px] = fminf(fmaxf(accB[rr] * iw, 0.f), 1.f);
    }
}

extern "C" void kernel_launch(void* const* d_in, const int* in_sizes, int n_in,
                              void* d_out, int out_size, void* d_ws, size_t ws_size,
                              hipStream_t stream) {
    const float* rgb   = (const float*)d_in[0];
    const float* sigma = (const float*)d_in[1];
    float* out = (float*)d_out;

    const size_t need6 = (size_t)6 * NPX * sizeof(float4);
    const size_t need4 = (size_t)4 * NPX * sizeof(float4);
    int nslice = (ws_size >= need6) ? 6 : (ws_size >= need4 ? 4 : 0);

    if (nslice > 0) {
        float4* ws = (float4*)d_ws;
        dim3 grid(IW / TS, IH / TS, nslice);
        nlm_part<<<grid, dim3(256), 0, stream>>>(rgb, sigma, ws);
        nlm_combine<<<dim3(NPX / 256), dim3(256), 0, stream>>>(ws, out, nslice);
    } else {
        dim3 grid(IW / TS, IH / TS);
        nlm_mono<<<grid, dim3(256), 0, stream>>>(rgb, sigma, out);
    }
}